// Round 6
// baseline (302.423 us; speedup 1.0000x reference)
//
#include <hip/hip_runtime.h>
#include <cmath>

typedef unsigned short u16;
typedef __attribute__((ext_vector_type(8))) short bf16x8;
typedef __attribute__((ext_vector_type(4))) float f32x4;
typedef __attribute__((ext_vector_type(16))) float f32x16;

#define MFMA(a,b,c)   __builtin_amdgcn_mfma_f32_16x16x32_bf16((a),(b),(c),0,0,0)
#define MFMA32(a,b,c) __builtin_amdgcn_mfma_f32_32x32x16_bf16((a),(b),(c),0,0,0)

__device__ __forceinline__ float bf2f(u16 u){ return __uint_as_float(((unsigned)u)<<16); }
__device__ __forceinline__ u16 f2bf(float f){
  unsigned x = __float_as_uint(f);
  return (u16)((x + 0x7FFFu + ((x>>16)&1u)) >> 16);
}

__device__ __forceinline__ void gll16(const u16* g, u16* l){
  __builtin_amdgcn_global_load_lds((const __attribute__((address_space(1))) unsigned*)g,
                                   (__attribute__((address_space(3))) unsigned*)l, 16, 0, 0);
}

// ---------- prep: transpose + re-layout to slab-contiguous bf16 ----------
// w1 (E,D,H) -> w1t2[e][kd=d>>4][h][d&15]  (slab (e,ks,h-half) = 8KB contiguous)
// w2 (E,H,D) -> w2t2[e][kh=h>>4][d][h&15]
__global__ __launch_bounds__(256) void k_transpose(const float* __restrict__ w1,
        const float* __restrict__ w2, u16* __restrict__ w1t2, u16* __restrict__ w2t2){
  __shared__ u16 t[64][66];
  int b = blockIdx.x;
  int c0 = threadIdx.x & 63, r0 = threadIdx.x >> 6;
  if (b < 192){            // w1: src (D=256 x H=512)
    int e = b >> 5, tl = b & 31;
    int tr = (tl >> 3) << 6, tc = (tl & 7) << 6;
    const float* src = w1 + (size_t)e*131072;
    u16* dst = w1t2 + (size_t)e*131072;
    #pragma unroll
    for (int i=0;i<16;++i){
      int r = r0 + i*4;
      t[c0][r] = f2bf(src[(size_t)(tr+r)*512 + tc + c0]);   // coalesced along H
    }
    __syncthreads();
    #pragma unroll
    for (int i=0;i<16;++i){
      int cc = r0 + i*4;
      int h = tc + cc, d = tr + c0;
      dst[(size_t)((d>>4)*512 + h)*16 + (d&15)] = t[cc][c0];
    }
  } else {                 // w2: src (H=512 x D=256)
    int bb = b - 192;
    int e = bb >> 5, tl = bb & 31;
    int tr = (tl >> 2) << 6, tc = (tl & 3) << 6;
    const float* src = w2 + (size_t)e*131072;
    u16* dst = w2t2 + (size_t)e*131072;
    #pragma unroll
    for (int i=0;i<16;++i){
      int r = r0 + i*4;
      t[c0][r] = f2bf(src[(size_t)(tr+r)*256 + tc + c0]);   // coalesced along D
    }
    __syncthreads();
    #pragma unroll
    for (int i=0;i<16;++i){
      int cc = r0 + i*4;
      int d = tc + cc, h = tr + c0;
      dst[(size_t)((h>>4)*256 + d)*16 + (h&15)] = t[cc][c0];
    }
  }
}

// rw1 (261,256): first 256 rows -> [j][d] hi/lo bf16; rows 256..260 + rb1 folded into regb[b][j].
__global__ void k_prep_rw1(const float* __restrict__ rw1, const float* __restrict__ rb1,
                           const float* __restrict__ regime,
                           u16* __restrict__ rwh, u16* __restrict__ rwl,
                           float* __restrict__ regb){
  int idx = blockIdx.x*256 + threadIdx.x;  // 65536 + 2048 total
  if (idx < 65536){
    int dd = idx & 255, j = idx >> 8;
    float w = rw1[dd*256 + j];
    u16 hi = f2bf(w);
    rwh[idx] = hi;
    rwl[idx] = f2bf(w - bf2f(hi));
  } else {
    int i = idx - 65536; int j = i & 255, b = i >> 8;
    float v = rb1[j];
    #pragma unroll
    for (int r=0;r<5;++r) v += regime[b*5+r]*rw1[(256+r)*256 + j];
    regb[b*256 + j] = v;
  }
}

// ---------- LayerNorm: x -> xn hi/lo bf16 (wave per token) ----------
__global__ __launch_bounds__(256) void k_ln(const float* __restrict__ x,
        const float* __restrict__ g, const float* __restrict__ bta,
        u16* __restrict__ xh, u16* __restrict__ xl){
  int wv = threadIdx.x >> 6, lane = threadIdx.x & 63;
  int t = blockIdx.x*4 + wv;
  float4 v = ((const float4*)(x + (size_t)t*256))[lane];
  float s  = v.x+v.y+v.z+v.w;
  float ss = v.x*v.x+v.y*v.y+v.z*v.z+v.w*v.w;
  #pragma unroll
  for (int m=32;m>=1;m>>=1){ s += __shfl_xor(s,m); ss += __shfl_xor(ss,m); }
  float mu  = s*(1.f/256.f);
  float var = ss*(1.f/256.f) - mu*mu;
  float inv = 1.f / sqrtf(var + 1e-5f);
  float4 gv = ((const float4*)g)[lane];
  float4 bv = ((const float4*)bta)[lane];
  float xv[4] = {v.x,v.y,v.z,v.w};
  float gg[4] = {gv.x,gv.y,gv.z,gv.w};
  float bb[4] = {bv.x,bv.y,bv.z,bv.w};
  u16 hh[4], ll[4];
  #pragma unroll
  for (int q=0;q<4;++q){
    float xn = (xv[q]-mu)*inv*gg[q] + bb[q];
    u16 h = f2bf(xn);
    hh[q] = h;
    ll[q] = f2bf(xn - bf2f(h));
  }
  ((ushort4*)(xh + (size_t)t*256))[lane] = make_ushort4(hh[0],hh[1],hh[2],hh[3]);
  ((ushort4*)(xl + (size_t)t*256))[lane] = make_ushort4(ll[0],ll[1],ll[2],ll[3]);
}

// ---------- router GEMM (hi/lo MFMA, weight frags direct from L2) ----------
__global__ __launch_bounds__(256,2) void k_router(const u16* __restrict__ xh, const u16* __restrict__ xl,
        const u16* __restrict__ rwh, const u16* __restrict__ rwl,
        const float* __restrict__ regb, float* __restrict__ hid){
  __shared__ u16 ash[64*264];
  __shared__ u16 asl[64*264];
  int tid = threadIdx.x;
  int lane = tid & 63, wv = tid >> 6;
  int lr = lane & 15, lg = lane >> 4;
  int tb = blockIdx.x * 64;
  for (int c = tid; c < 2048; c += 256){
    int r = c >> 5, cc = c & 31;
    *(uint4*)(&ash[r*264 + cc*8]) = *(const uint4*)(xh + (size_t)(tb+r)*256 + cc*8);
    *(uint4*)(&asl[r*264 + cc*8]) = *(const uint4*)(xl + (size_t)(tb+r)*256 + cc*8);
  }
  __syncthreads();
  f32x4 acc[4][4];
  #pragma unroll
  for (int mf=0;mf<4;++mf)
    #pragma unroll
    for (int nf=0;nf<4;++nf) acc[mf][nf] = (f32x4){0.f,0.f,0.f,0.f};

  const u16* bhb = rwh + (size_t)wv*64*256;
  const u16* blb = rwl + (size_t)wv*64*256;
  #pragma unroll
  for (int kt=0;kt<8;++kt){
    bf16x8 ah[4], al[4], bh[4], bl[4];
    #pragma unroll
    for (int nf=0;nf<4;++nf){
      bh[nf] = *(const bf16x8*)(bhb + (size_t)(nf*16+lr)*256 + kt*32 + lg*8);
      bl[nf] = *(const bf16x8*)(blb + (size_t)(nf*16+lr)*256 + kt*32 + lg*8);
    }
    #pragma unroll
    for (int mf=0;mf<4;++mf){
      ah[mf] = *(const bf16x8*)(&ash[(mf*16+lr)*264 + kt*32 + lg*8]);
      al[mf] = *(const bf16x8*)(&asl[(mf*16+lr)*264 + kt*32 + lg*8]);
    }
    #pragma unroll
    for (int mf=0;mf<4;++mf)
      #pragma unroll
      for (int nf=0;nf<4;++nf){
        acc[mf][nf] = MFMA(ah[mf], bh[nf], acc[mf][nf]);
        acc[mf][nf] = MFMA(al[mf], bh[nf], acc[mf][nf]);
        acc[mf][nf] = MFMA(ah[mf], bl[nf], acc[mf][nf]);
      }
  }
  int b = tb >> 12;
  #pragma unroll
  for (int mf=0;mf<4;++mf)
    #pragma unroll
    for (int nf=0;nf<4;++nf){
      int j = wv*64 + nf*16 + lr;
      float rbv = regb[b*256 + j];
      #pragma unroll
      for (int r=0;r<4;++r){
        int t = tb + mf*16 + lg*4 + r;
        float v = acc[mf][nf][r] + rbv;
        hid[(size_t)t*256 + j] = v/(1.f+__expf(-v));
      }
    }
}

// ---------- logits + top2 + gates + aux partials ----------
__global__ __launch_bounds__(256) void k_logits(const float* __restrict__ hid,
        const float* __restrict__ rw2, const float* __restrict__ rb2,
        float* __restrict__ selw, float* __restrict__ partials){
  __shared__ float psum[6], pcnt[6];
  int tid = threadIdx.x;
  if (tid < 6){ psum[tid]=0.f; pcnt[tid]=0.f; }
  __syncthreads();
  int lane = tid & 63;
  int lr = lane & 15, lg = lane >> 4;
  int t = blockIdx.x*16 + (tid>>6)*4 + lg;
  float lacc[6] = {0.f,0.f,0.f,0.f,0.f,0.f};
  const float4* hp = (const float4*)(hid + (size_t)t*256);
  #pragma unroll
  for (int p=0;p<4;++p){
    float4 h4 = hp[p*16 + lr];
    float hv[4] = {h4.x,h4.y,h4.z,h4.w};
    int j0 = (p*16+lr)*4;
    #pragma unroll
    for (int q=0;q<4;++q)
      #pragma unroll
      for (int e=0;e<6;++e) lacc[e] += hv[q]*rw2[(j0+q)*6+e];
  }
  #pragma unroll
  for (int m=1;m<16;m<<=1)
    #pragma unroll
    for (int e=0;e<6;++e) lacc[e] += __shfl_xor(lacc[e], m);
  if (lr == 0){
    float lgv[6];
    #pragma unroll
    for (int e=0;e<6;++e) lgv[e] = lacc[e] + rb2[e];
    int i0=0; float v0=lgv[0];
    #pragma unroll
    for (int e=1;e<6;++e) if (lgv[e] > v0){ v0=lgv[e]; i0=e; }
    int i1=-1; float v1=-1e30f;
    #pragma unroll
    for (int e=0;e<6;++e) if (e!=i0 && lgv[e] > v1){ v1=lgv[e]; i1=e; }
    float ex = expf(v1-v0);
    float w0 = 1.f/(1.f+ex), w1 = ex/(1.f+ex);
    #pragma unroll
    for (int e=0;e<6;++e) selw[(size_t)t*6+e] = (e==i0)? w0 : (e==i1)? w1 : 0.f;
    float ps=0.f, p[6];
    #pragma unroll
    for (int e=0;e<6;++e){ p[e]=expf(lgv[e]-v0); ps+=p[e]; }
    float rinv = 1.f/ps;
    #pragma unroll
    for (int e=0;e<6;++e) atomicAdd(&psum[e], p[e]*rinv);
    atomicAdd(&pcnt[i0], 1.f);
  }
  __syncthreads();
  if (tid < 6){
    partials[blockIdx.x*12 + tid] = psum[tid];
    partials[blockIdx.x*12 + 6 + tid] = pcnt[tid];
  }
}

__global__ __launch_bounds__(256) void k_aux(const float* __restrict__ partials, float* __restrict__ outp){
  __shared__ float a[12];
  int tid = threadIdx.x;
  if (tid < 12) a[tid] = 0.f;
  __syncthreads();
  int col = tid & 15, seg = tid >> 4;
  if (col < 12){
    float s = 0.f;
    for (int i=seg; i<2048; i+=16) s += partials[i*12+col];
    atomicAdd(&a[col], s);
  }
  __syncthreads();
  if (tid==0){
    float aux=0.f;
    #pragma unroll
    for (int e=0;e<6;++e) aux += a[e]*a[6+e];
    aux *= 0.01f*6.f/(32768.f*32768.f);
    outp[8388608] = aux;
  }
}

// ---------- fused all-expert MLP v4: 32x32x16 MFMA, slab pipeline, counted vmcnt ----------
// LDS (u16 units): xs [0,32768) 128tok x 256d swz ^(row&7)
//                  hs [32768,65536) 128tok x 256h swz ^(row&7)
//                  stage [65536, 65536+3*4096)  three 8KB slabs
// slabs ci=0..383: e=ci>>6, hh=(ci>>5)&1, s=ci&31; s<16: G1 (w1, ks=s), else G2 (w2, ks=s-16)
__device__ __forceinline__ void stage_slab(int ci, u16* lds,
        const u16* __restrict__ w1t2, const u16* __restrict__ w2t2, int tid){
  int e = ci >> 6, hh = (ci >> 5) & 1, s = ci & 31;
  const u16* src = (s < 16)
    ? (w1t2 + ((((size_t)e*16 + s)*512 + hh*256) << 4))
    : (w2t2 + ((((size_t)e*32 + hh*16 + (s-16))*256) << 4));
  gll16(src + tid*8, lds + 65536 + (ci % 3)*4096 + tid*8);
}

__global__ __launch_bounds__(512,2) void k_experts(const u16* __restrict__ xh,
        const u16* __restrict__ w1t2, const u16* __restrict__ w2t2,
        const float* __restrict__ b1g, const float* __restrict__ b2g,
        const float* __restrict__ selw, const float* __restrict__ xg,
        float* __restrict__ outp){
  __shared__ u16 lds[77824];                 // 152 KB
  int tid = threadIdx.x;                     // 8 waves
  int lane = tid & 63, wv = tid >> 6;
  int l31 = lane & 31, l5 = lane >> 5;
  int wh = wv >> 1, wt = wv & 1;             // wh: h/d quad, wt: token half
  int tb = blockIdx.x * 128;

  // gate weights to registers (per-lane token = col of C tiles)
  float gw[2][6];
  #pragma unroll
  for (int tt=0;tt<2;++tt){
    int t = tb + wt*64 + tt*32 + l31;
    #pragma unroll
    for (int e=0;e<6;++e) gw[tt][e] = selw[(size_t)t*6 + e];
  }
  // stage xs: linear dest, inverse-swizzled source
  #pragma unroll
  for (int j=0;j<8;++j){
    int row = j*16 + wv*2 + l5;
    int ss = l31 ^ (row & 7);
    gll16(xh + (size_t)(tb+row)*256 + ss*8, lds + j*4096 + tid*8);
  }
  stage_slab(0, lds, w1t2, w2t2, tid);
  stage_slab(1, lds, w1t2, w2t2, tid);

  f32x16 oacc[2][2];
  #pragma unroll
  for (int d=0;d<2;++d)
    #pragma unroll
    for (int tt=0;tt<2;++tt) oacc[d][tt] = (f32x16)(0.f);

  int ci = 0;
  for (int e=0;e<6;++e){
    for (int hh=0;hh<2;++hh){
      // ================= GEMM1: acc1[h-tile][t-tile], K = d = 256 =================
      f32x16 acc1[2][2];
      #pragma unroll
      for (int a=0;a<2;++a)
        #pragma unroll
        for (int tt=0;tt<2;++tt) acc1[a][tt] = (f32x16)(0.f);
      for (int ks=0;ks<16;++ks){
        if (ci <= 382) asm volatile("s_waitcnt vmcnt(1)" ::: "memory");
        else           asm volatile("s_waitcnt vmcnt(0)" ::: "memory");
        __builtin_amdgcn_s_barrier();
        __builtin_amdgcn_sched_barrier(0);
        if (ci + 2 < 384) stage_slab(ci+2, lds, w1t2, w2t2, tid);
        const u16* sb = &lds[65536 + (ci % 3)*4096];
        bf16x8 af[2], bx[2];
        #pragma unroll
        for (int a=0;a<2;++a)
          af[a] = *(const bf16x8*)&sb[(wh*64 + a*32 + l31)*16 + l5*8];
        #pragma unroll
        for (int tt=0;tt<2;++tt){
          int row = wt*64 + tt*32 + l31;
          int slot = (ks*2 + l5) ^ (row & 7);
          bx[tt] = *(const bf16x8*)&lds[row*256 + slot*8];
        }
        __builtin_amdgcn_s_setprio(1);
        #pragma unroll
        for (int a=0;a<2;++a)
          #pragma unroll
          for (int tt=0;tt<2;++tt)
            acc1[a][tt] = MFMA32(af[a], bx[tt], acc1[a][tt]);
        __builtin_amdgcn_s_setprio(0);
        ++ci;
      }
      // ---- epilogue: bias + silu -> hs (swizzled b64 writes) ----
      #pragma unroll
      for (int a=0;a<2;++a){
        int hbase = wh*64 + a*32;
        #pragma unroll
        for (int rq=0;rq<4;++rq){
          float4 b4 = *(const float4*)(b1g + (size_t)e*512 + hh*256 + hbase + rq*8 + l5*4);
          float bb[4] = {b4.x,b4.y,b4.z,b4.w};
          #pragma unroll
          for (int tt=0;tt<2;++tt){
            float sv[4];
            #pragma unroll
            for (int q=0;q<4;++q){
              float v = acc1[a][tt][rq*4+q] + bb[q];
              sv[q] = v/(1.f+__expf(-v));
            }
            unsigned p0 = (unsigned)f2bf(sv[0]) | ((unsigned)f2bf(sv[1])<<16);
            unsigned p1 = (unsigned)f2bf(sv[2]) | ((unsigned)f2bf(sv[3])<<16);
            int row = wt*64 + tt*32 + l31;
            int slot = (wh*8 + a*4 + rq) ^ (row & 7);
            *(uint2*)&lds[32768 + row*256 + slot*8 + l5*4] = make_uint2(p0,p1);
          }
        }
      }
      asm volatile("s_waitcnt lgkmcnt(0)" ::: "memory");
      __builtin_amdgcn_s_barrier();
      __builtin_amdgcn_sched_barrier(0);
      // ================= GEMM2: acc2[d-tile][t-tile], K = h-half = 256 =================
      f32x16 acc2[2][2];
      #pragma unroll
      for (int d=0;d<2;++d)
        #pragma unroll
        for (int tt=0;tt<2;++tt) acc2[d][tt] = (f32x16)(0.f);
      for (int ks=0;ks<16;++ks){
        if (ci <= 382) asm volatile("s_waitcnt vmcnt(1)" ::: "memory");
        else           asm volatile("s_waitcnt vmcnt(0)" ::: "memory");
        __builtin_amdgcn_s_barrier();
        __builtin_amdgcn_sched_barrier(0);
        if (ci + 2 < 384) stage_slab(ci+2, lds, w1t2, w2t2, tid);
        const u16* sb = &lds[65536 + (ci % 3)*4096];
        bf16x8 wf[2], hf[2];
        #pragma unroll
        for (int d=0;d<2;++d)
          wf[d] = *(const bf16x8*)&sb[(wh*64 + d*32 + l31)*16 + l5*8];
        #pragma unroll
        for (int tt=0;tt<2;++tt){
          int row = wt*64 + tt*32 + l31;
          int slot = (ks*2 + l5) ^ (row & 7);
          hf[tt] = *(const bf16x8*)&lds[32768 + row*256 + slot*8];
        }
        __builtin_amdgcn_s_setprio(1);
        #pragma unroll
        for (int d=0;d<2;++d)
          #pragma unroll
          for (int tt=0;tt<2;++tt)
            acc2[d][tt] = MFMA32(wf[d], hf[tt], acc2[d][tt]);
        __builtin_amdgcn_s_setprio(0);
        ++ci;
      }
      // ---- fold into gated accumulator ----
      #pragma unroll
      for (int tt=0;tt<2;++tt){
        float g = gw[tt][e];
        #pragma unroll
        for (int d=0;d<2;++d)
          #pragma unroll
          for (int r=0;r<16;++r)
            oacc[d][tt][r] += g*acc2[d][tt][r];
      }
      if (hh==1){
        #pragma unroll
        for (int d=0;d<2;++d)
          #pragma unroll
          for (int rq=0;rq<4;++rq){
            float4 b4 = *(const float4*)(b2g + (size_t)e*256 + wh*64 + d*32 + rq*8 + l5*4);
            float bb[4] = {b4.x,b4.y,b4.z,b4.w};
            #pragma unroll
            for (int tt=0;tt<2;++tt){
              float g = gw[tt][e];
              #pragma unroll
              for (int q=0;q<4;++q) oacc[d][tt][rq*4+q] += g*bb[q];
            }
          }
      }
    }
  }
  // ---- residual + store ----
  #pragma unroll
  for (int d=0;d<2;++d)
    #pragma unroll
    for (int tt=0;tt<2;++tt){
      int t = tb + wt*64 + tt*32 + l31;
      #pragma unroll
      for (int rq=0;rq<4;++rq){
        int d0 = wh*64 + d*32 + rq*8 + l5*4;
        float4 xv = *(const float4*)(xg + (size_t)t*256 + d0);
        float4 o;
        o.x = xv.x + oacc[d][tt][rq*4+0];
        o.y = xv.y + oacc[d][tt][rq*4+1];
        o.z = xv.z + oacc[d][tt][rq*4+2];
        o.w = xv.w + oacc[d][tt][rq*4+3];
        *(float4*)(outp + (size_t)t*256 + d0) = o;
      }
    }
}

extern "C" void kernel_launch(void* const* d_in, const int* in_sizes, int n_in,
                              void* d_out, int out_size, void* d_ws, size_t ws_size,
                              hipStream_t stream){
  const float* x      = (const float*)d_in[0];
  const float* regime = (const float*)d_in[1];
  const float* ln_g   = (const float*)d_in[2];
  const float* ln_b   = (const float*)d_in[3];
  const float* w1     = (const float*)d_in[4];
  const float* b1     = (const float*)d_in[5];
  const float* w2     = (const float*)d_in[6];
  const float* b2     = (const float*)d_in[7];
  const float* rw1    = (const float*)d_in[8];
  const float* rb1    = (const float*)d_in[9];
  const float* rw2    = (const float*)d_in[10];
  const float* rb2    = (const float*)d_in[11];
  float* outp = (float*)d_out;
  char* ws = (char*)d_ws;

  u16*   w1t2 = (u16*)(ws + 0);          // 1,572,864
  u16*   w2t2 = (u16*)(ws + 1572864);    // 1,572,864
  u16*   rwh  = (u16*)(ws + 3145728);    // 131,072
  u16*   rwl  = (u16*)(ws + 3276800);    // 131,072
  float* regb = (float*)(ws + 3407872);  // 8,192
  u16*   xh   = (u16*)(ws + 3416064);    // 16,777,216
  u16*   xl   = (u16*)(ws + 20193280);   // 16,777,216 (dead after k_router)
  float* part = (float*)(ws + 20193280); // 98,304 — overlays xl, written after router
  float* hid  = (float*)(ws + 36970496); // 33,554,432
  float* selw = (float*)(ws + 70524928); // 786,432

  k_transpose<<<384,256,0,stream>>>(w1, w2, w1t2, w2t2);
  k_prep_rw1<<<264,256,0,stream>>>(rw1, rb1, regime, rwh, rwl, regb);
  k_ln<<<8192,256,0,stream>>>(x, ln_g, ln_b, xh, xl);
  k_router<<<512,256,0,stream>>>(xh, xl, rwh, rwl, regb, hid);
  k_logits<<<2048,256,0,stream>>>(hid, rw2, rb2, selw, part);
  k_aux<<<1,256,0,stream>>>(part, outp);
  k_experts<<<256,512,0,stream>>>(xh, w1t2, w2t2, b1, b2, selw, x, outp);
}